// Round 2
// baseline (907.203 us; speedup 1.0000x reference)
//
#include <hip/hip_runtime.h>
#include <hip/hip_bf16.h>
#include <math.h>

typedef unsigned short u16;
typedef __attribute__((ext_vector_type(8))) short short8;
typedef __attribute__((ext_vector_type(4))) float f32x4;

#define T_STEPS 10
#define NB 8
#define HH 64
#define WW 64
#define FF 64
#define NGATE 256
#define HP 66
#define PIX (NB*HH*WW)          // 32768
#define GEMM_BLOCKS (PIX/128)   // 256: one block = 2 image rows

__device__ __forceinline__ u16 f2bf(float f) {
    unsigned u = __float_as_uint(f);
    u += 0x7FFF + ((u >> 16) & 1);   // round-to-nearest-even
    return (u16)(u >> 16);
}
__device__ __forceinline__ float hsig(float x) {
    return fminf(fmaxf(0.2f * x + 0.5f, 0.0f), 1.0f);
}
__device__ __forceinline__ float ftanh(float x) {
    // tanh(x) = 1 - 2/(exp(2x)+1); exp overflow -> +inf -> 1, underflow -> -1.
    float e = __expf(2.0f * x);
    return 1.0f - 2.0f / (e + 1.0f);
}

// Transpose fp32 [K][256] weight(s) -> bf16 BT [256][K]. For K=1152 the first
// 576 rows come from W0 (input kernel) and the rest from W1 (recurrent kernel).
__global__ void wtrans_kernel(const float* __restrict__ W0,
                              const float* __restrict__ W1,
                              u16* __restrict__ BT, int K) {
    int total = K * NGATE;
    for (int o = blockIdx.x * blockDim.x + threadIdx.x; o < total;
         o += gridDim.x * blockDim.x) {
        int n = o / K, k = o - n * K;
        float v = (k < 576) ? W0[k * NGATE + n] : W1[(k - 576) * NGATE + n];
        BT[o] = f2bf(v);
    }
}

// Implicit-GEMM conv (3x3 SAME) + fused ConvLSTM gate update.
// Block: 128 pixels (2 image rows) x 256 gate-channels. 512 threads, 8 waves.
// Wave w: row-half (w>>2), f-quarter (w&3); each wave computes 64 rows x
// (16 f x 4 gates) via 16 x 16x16x32 bf16 MFMAs per K=64 chunk.
// Layer-0 additionally fuses the Cin=1 input conv (fp32 exact) in the epilogue.
__global__ __launch_bounds__(512, 2)
void gemm_lstm_kernel(const u16* __restrict__ Ah0,  // taps 0..8 source (padded)
                      const u16* __restrict__ Ah1,  // taps 9..17 source or null
                      const u16* __restrict__ BT,   // [256][K]
                      int K,
                      const float* __restrict__ xsrc,  // (B,T,64,64) or null
                      const float* __restrict__ k0w,   // (9,256) or null
                      const float* __restrict__ bias,  // [256]
                      int t,
                      float* __restrict__ cbuf,        // [PIX][64]
                      u16* __restrict__ hpad_out,      // padded (8,66,66,64)
                      float* __restrict__ outh,
                      float* __restrict__ outc,
                      int write_out) {
    __shared__ __align__(16) u16 sA[128][72];
    __shared__ __align__(16) u16 sB[256][72];
    __shared__ float xs[4][66];

    int tid = threadIdx.x;
    int wave = tid >> 6, lane = tid & 63;
    int mhalf = wave >> 2, fq = wave & 3;
    int blk = blockIdx.x;
    int b = blk >> 5, y0 = (blk & 31) * 2;   // rows y0, y0+1

    // Stage x halo rows (layer 0 only); read only in epilogue, so the K-loop
    // barriers cover it.
    if (xsrc && tid < 4 * 66) {
        int dyi = tid / 66, xx = tid - dyi * 66;
        int yy = y0 + dyi - 1, col = xx - 1;
        float v = 0.0f;
        if (yy >= 0 && yy < HH && col >= 0 && col < WW)
            v = xsrc[(((size_t)b * T_STEPS + t) * HH + yy) * WW + col];
        xs[dyi][xx] = v;
    }

    f32x4 acc[4][4];
#pragma unroll
    for (int mt = 0; mt < 4; ++mt)
#pragma unroll
        for (int g = 0; g < 4; ++g)
            acc[mt][g] = (f32x4){0.f, 0.f, 0.f, 0.f};

    int nchunks = K >> 6;
    int a_row = tid >> 2, a_q = tid & 3;     // A staging: row, 16-ch quarter
    int b_row0 = tid >> 3, b_part = tid & 7; // B staging: row base, 8-k part

    for (int kc = 0; kc < nchunks; ++kc) {
        int tau = (kc < 9) ? kc : kc - 9;
        const u16* src = (kc < 9) ? Ah0 : Ah1;
        int dy = tau / 3 - 1, dx = tau % 3 - 1;
        {   // A tile: 128 px x 64 ch for this tap (halo makes it branch-free)
            int yy = y0 + (a_row >> 6) + dy + 1;
            int xx = (a_row & 63) + dx + 1;
            const u16* gp = src + (((size_t)(b * HP + yy)) * HP + xx) * FF + a_q * 16;
            *(uint4*)&sA[a_row][a_q * 16]     = *(const uint4*)gp;
            *(uint4*)&sA[a_row][a_q * 16 + 8] = *(const uint4*)(gp + 8);
        }
        {   // B tile: 256 n x 64 k
            const u16* gb = BT + (size_t)kc * 64 + b_part * 8;
#pragma unroll
            for (int pass = 0; pass < 4; ++pass) {
                int n = pass * 64 + b_row0;
                *(uint4*)&sB[n][b_part * 8] = *(const uint4*)(gb + (size_t)n * K);
            }
        }
        __syncthreads();
#pragma unroll
        for (int ks = 0; ks < 2; ++ks) {
            short8 aF[4], bF[4];
            int ko = ks * 32 + (lane >> 4) * 8;
#pragma unroll
            for (int mt = 0; mt < 4; ++mt)
                aF[mt] = *(const short8*)&sA[mhalf * 64 + mt * 16 + (lane & 15)][ko];
#pragma unroll
            for (int g = 0; g < 4; ++g)
                bF[g] = *(const short8*)&sB[g * 64 + fq * 16 + (lane & 15)][ko];
#pragma unroll
            for (int mt = 0; mt < 4; ++mt)
#pragma unroll
                for (int g = 0; g < 4; ++g)
                    acc[mt][g] = __builtin_amdgcn_mfma_f32_16x16x32_bf16(
                        aF[mt], bF[g], acc[mt][g], 0, 0, 0);
        }
        __syncthreads();
    }

    // Epilogue. Wave's f-cols: fq*16 + (lane&15), across all 4 gate n-tiles,
    // so the gate update is lane-local.
    int f = fq * 16 + (lane & 15);
    int quad = lane >> 4;
    float bi = bias[f], bff = bias[64 + f], bg = bias[128 + f], bo = bias[192 + f];
    float wk[4][9];
    if (xsrc) {
#pragma unroll
        for (int g = 0; g < 4; ++g)
#pragma unroll
            for (int tau = 0; tau < 9; ++tau)
                wk[g][tau] = k0w[tau * NGATE + g * 64 + f];
    }
#pragma unroll
    for (int mt = 0; mt < 4; ++mt) {
#pragma unroll
        for (int r = 0; r < 4; ++r) {
            int row = mhalf * 64 + mt * 16 + quad * 4 + r;
            int y_loc = row >> 6, xcol = row & 63;
            int y = y0 + y_loc;
            size_t p = ((size_t)b * 64 + y) * 64 + xcol;
            float zi = acc[mt][0][r] + bi;
            float zf = acc[mt][1][r] + bff;
            float zg = acc[mt][2][r] + bg;
            float zo = acc[mt][3][r] + bo;
            if (xsrc) {   // fused layer-0 input conv, fp32 exact
                float xv[9];
#pragma unroll
                for (int tau = 0; tau < 9; ++tau)
                    xv[tau] = xs[y_loc + tau / 3][xcol + tau % 3];
#pragma unroll
                for (int tau = 0; tau < 9; ++tau) {
                    zi += xv[tau] * wk[0][tau];
                    zf += xv[tau] * wk[1][tau];
                    zg += xv[tau] * wk[2][tau];
                    zo += xv[tau] * wk[3][tau];
                }
            }
            float cold = cbuf[p * FF + f];
            float cn = hsig(zf) * cold + hsig(zi) * ftanh(zg);
            float hn = hsig(zo) * ftanh(cn);
            cbuf[p * FF + f] = cn;
            hpad_out[(((size_t)(b * HP + y + 1)) * HP + (xcol + 1)) * FF + f] = f2bf(hn);
            if (write_out) { outh[p * FF + f] = hn; outc[p * FF + f] = cn; }
        }
    }
}

extern "C" void kernel_launch(void* const* d_in, const int* in_sizes, int n_in,
                              void* d_out, int out_size, void* d_ws, size_t ws_size,
                              hipStream_t stream) {
    const float* x   = (const float*)d_in[0];
    const float* k0  = (const float*)d_in[1];
    const float* rk0 = (const float*)d_in[2];
    const float* b0  = (const float*)d_in[3];
    const float* k1  = (const float*)d_in[4];
    const float* rk1 = (const float*)d_in[5];
    const float* b1  = (const float*)d_in[6];
    float* out = (float*)d_out;

    char* ws = (char*)d_ws;
    const size_t HPAD_BYTES = (size_t)NB * HP * HP * FF * 2;  // 4,460,544
    const size_t C_BYTES    = (size_t)PIX * FF * 4;           // 8,388,608

    u16* h0p[2]; u16* h1p[2];
    h0p[0] = (u16*)(ws);
    h0p[1] = (u16*)(ws + HPAD_BYTES);
    h1p[0] = (u16*)(ws + 2 * HPAD_BYTES);
    h1p[1] = (u16*)(ws + 3 * HPAD_BYTES);
    float* c0 = (float*)(ws + 4 * HPAD_BYTES);
    float* c1 = (float*)(ws + 4 * HPAD_BYTES + C_BYTES);
    u16* B0T  = (u16*)(ws + 4 * HPAD_BYTES + 2 * C_BYTES);
    u16* B1T  = (u16*)(ws + 4 * HPAD_BYTES + 2 * C_BYTES + (size_t)576 * 256 * 2);

    // Zero h (incl. halo == SAME padding) and c states; ws is poisoned 0xAA.
    hipMemsetAsync(ws, 0, 4 * HPAD_BYTES + 2 * C_BYTES, stream);

    // Weights -> bf16, transposed to [N][K] once per launch.
    wtrans_kernel<<<256, 256, 0, stream>>>(rk0, rk0, B0T, 576);
    wtrans_kernel<<<256, 256, 0, stream>>>(k1, rk1, B1T, 1152);

    float* oh0 = out;
    float* oc0 = out + (size_t)PIX * FF;
    float* oh1 = out + 2 * (size_t)PIX * FF;
    float* oc1 = out + 3 * (size_t)PIX * FF;

    for (int t = 0; t < T_STEPS; ++t) {
        int par = t & 1;
        int wo = (t == T_STEPS - 1) ? 1 : 0;
        // Layer 0: z = conv(x_t,k0)+b0 (fused in epilogue) + conv(h0_prev,rk0).
        gemm_lstm_kernel<<<GEMM_BLOCKS, 512, 0, stream>>>(
            h0p[par], nullptr, B0T, 576, x, k0, b0, t,
            c0, h0p[par ^ 1], oh0, oc0, wo);
        // Layer 1: z = conv(h0_new, k1) + conv(h1_prev, rk1) + b1.
        gemm_lstm_kernel<<<GEMM_BLOCKS, 512, 0, stream>>>(
            h0p[par ^ 1], h1p[par], B1T, 1152, nullptr, nullptr, b1, 0,
            c1, h1p[par ^ 1], oh1, oc1, wo);
    }
}